// Round 10
// baseline (396.513 us; speedup 1.0000x reference)
//
#include <hip/hip_runtime.h>
#include <hip/hip_bf16.h>

// Problem constants (reference): IN_DIM = HID = 64, K = 3, NCLS = 10.
// All compute fp32. Output fp32 (B*10).
//
// CSR build (no global atomics; counting sort by dst):
//   P=16 node partitions (PART=6272), XCD-pinned (p = blockIdx % P keeps
//   partition p on XCD p%8 -> csr writes merge in one L2; verified R3->R6:
//   fill2 WRITE_SIZE 46MB -> 7.5MB).  MCH=64 edge chunks.
//   u8 chunk-offset metadata; u16-packed LDS counters + int4 edge loads
//   (R9: hist2 off the top-5).
//
// GEMM: W in 64 VGPRs (lane=column), wave-uniform scalar row loads, 4 rows
// per wave per iteration.  R9 showed 64-thread blocks cap occupancy at ~6
// waves/CU (latency-bound, VALUBusy 17%) -> 256-thread blocks = 4
// independent waves per workgroup for ~4x latency hiding.

#define PART 6272
#define HALFP (PART / 2)
#define MCH  64

// --------------------------- merged src+dst histogram (one edge pass)
__global__ void k_hist2(const int* __restrict__ esrc, const int* __restrict__ edst,
                        unsigned char* __restrict__ hd, unsigned char* __restrict__ hs,
                        int N, int E, int P) {
  __shared__ unsigned int ld[HALFP];
  __shared__ unsigned int ls[HALFP];
  const int b = blockIdx.x;
  const int p = b % P;
  const int m = b / P;
  const int base = p * PART;
  const int lim = min(PART, N - base);
  for (int i = threadIdx.x; i < HALFP; i += blockDim.x) { ld[i] = 0u; ls[i] = 0u; }
  __syncthreads();
  const long long cb = (long long)m * E / MCH;
  const long long ce = (long long)(m + 1) * E / MCH;
  const long long a0 = min((cb + 3) & ~3LL, ce);
  const long long nv = (ce - a0) >> 2;
  for (long long e = cb + threadIdx.x; e < a0; e += blockDim.x) {
    int d = edst[e] - base;
    if ((unsigned)d < (unsigned)lim) atomicAdd(&ld[d >> 1], 1u << ((d & 1) * 16));
    int s = esrc[e] - base;
    if ((unsigned)s < (unsigned)lim) atomicAdd(&ls[s >> 1], 1u << ((s & 1) * 16));
  }
  const int4* __restrict__ d4p = (const int4*)(edst + a0);
  const int4* __restrict__ s4p = (const int4*)(esrc + a0);
  for (long long i = threadIdx.x; i < nv; i += blockDim.x) {
    int4 d4 = d4p[i];
    int4 s4 = s4p[i];
    int d;
    d = d4.x - base; if ((unsigned)d < (unsigned)lim) atomicAdd(&ld[d >> 1], 1u << ((d & 1) * 16));
    d = d4.y - base; if ((unsigned)d < (unsigned)lim) atomicAdd(&ld[d >> 1], 1u << ((d & 1) * 16));
    d = d4.z - base; if ((unsigned)d < (unsigned)lim) atomicAdd(&ld[d >> 1], 1u << ((d & 1) * 16));
    d = d4.w - base; if ((unsigned)d < (unsigned)lim) atomicAdd(&ld[d >> 1], 1u << ((d & 1) * 16));
    d = s4.x - base; if ((unsigned)d < (unsigned)lim) atomicAdd(&ls[d >> 1], 1u << ((d & 1) * 16));
    d = s4.y - base; if ((unsigned)d < (unsigned)lim) atomicAdd(&ls[d >> 1], 1u << ((d & 1) * 16));
    d = s4.z - base; if ((unsigned)d < (unsigned)lim) atomicAdd(&ls[d >> 1], 1u << ((d & 1) * 16));
    d = s4.w - base; if ((unsigned)d < (unsigned)lim) atomicAdd(&ls[d >> 1], 1u << ((d & 1) * 16));
  }
  for (long long e = a0 + (nv << 2) + threadIdx.x; e < ce; e += blockDim.x) {
    int d = edst[e] - base;
    if ((unsigned)d < (unsigned)lim) atomicAdd(&ld[d >> 1], 1u << ((d & 1) * 16));
    int s = esrc[e] - base;
    if ((unsigned)s < (unsigned)lim) atomicAdd(&ls[s >> 1], 1u << ((s & 1) * 16));
  }
  __syncthreads();
  unsigned char* sd = hd + ((size_t)p * MCH + m) * PART;
  unsigned char* ss = hs + ((size_t)p * MCH + m) * PART;
  for (int i = threadIdx.x; i < lim; i += blockDim.x) {
    sd[i] = (unsigned char)((ld[i >> 1] >> ((i & 1) * 16)) & 0xffffu);
    ss[i] = (unsigned char)((ls[i >> 1] >> ((i & 1) * 16)) & 0xffffu);
  }
}

// ---------------- counts -> in-row prefix offsets (u8, in place) + degs/norms
__global__ void k_off(unsigned char* __restrict__ hd, const unsigned char* __restrict__ hs,
                      int* __restrict__ deg_d, float* __restrict__ norm_s,
                      float* __restrict__ norm_d, int N, int P) {
  int v = blockIdx.x * blockDim.x + threadIdx.x;
  if (v >= N) return;
  int p = v / PART, loc = v % PART;
  size_t base = (size_t)p * MCH * PART + loc;
  int run = 0;
#pragma unroll
  for (int m = 0; m < MCH; ++m) {
    int t = hd[base + (size_t)m * PART];
    hd[base + (size_t)m * PART] = (unsigned char)run;
    run += t;
  }
  int s = 0;
#pragma unroll
  for (int m = 0; m < MCH; ++m) s += hs[base + (size_t)m * PART];
  deg_d[v] = run;
  norm_d[v] = rsqrtf((float)max(run, 1));
  norm_s[v] = rsqrtf((float)max(s, 1));
}

// ------------------------------------------------------------ CSR scan
__global__ void k_scan1(const int* __restrict__ deg, int* __restrict__ rowptr,
                        int* __restrict__ bsum, int N) {
  __shared__ int sums[256];
  const int t = threadIdx.x;
  const int base = blockIdx.x * 2048 + t * 8;
  int loc[8];
  int tot = 0;
#pragma unroll
  for (int j = 0; j < 8; ++j) {
    int idx = base + j;
    loc[j] = tot;
    tot += (idx < N) ? deg[idx] : 0;
  }
  sums[t] = tot;
  __syncthreads();
  for (int off = 1; off < 256; off <<= 1) {
    int x = (t >= off) ? sums[t - off] : 0;
    __syncthreads();
    sums[t] += x;
    __syncthreads();
  }
  int excl = (t == 0) ? 0 : sums[t - 1];
#pragma unroll
  for (int j = 0; j < 8; ++j) {
    int idx = base + j;
    if (idx < N) rowptr[idx] = excl + loc[j];
  }
  if (t == 255) bsum[blockIdx.x] = sums[255];
}

__global__ void k_scan2(int* __restrict__ bsum, int nb) {
  int lane = threadIdx.x;
  int v = (lane < nb) ? bsum[lane] : 0;
  int inc = v;
#pragma unroll
  for (int off = 1; off < 64; off <<= 1) {
    int o = __shfl_up(inc, off, 64);
    if (lane >= off) inc += o;
  }
  if (lane < nb) bsum[lane] = inc - v;
}

__global__ void k_scan3(int* __restrict__ rowptr, const int* __restrict__ bsum, int N) {
  int v = blockIdx.x * blockDim.x + threadIdx.x;
  if (v < N) rowptr[v] += bsum[v >> 11];
}

// ----------------------------------------- fill (LDS cursors, no atomics)
__global__ void k_fill2(const int* __restrict__ esrc, const int* __restrict__ edst,
                        const unsigned char* __restrict__ hd, const int* __restrict__ rowptr,
                        int* __restrict__ csr, int N, int E, int P) {
  __shared__ int cur[PART];
  const int b = blockIdx.x;
  const int p = b % P;
  const int m = b / P;
  const int base = p * PART;
  const int lim = min(PART, N - base);
  const unsigned char* slice = hd + ((size_t)p * MCH + m) * PART;
  for (int i = threadIdx.x; i < lim; i += blockDim.x)
    cur[i] = rowptr[base + i] + (int)slice[i];
  __syncthreads();
  const long long cb = (long long)m * E / MCH;
  const long long ce = (long long)(m + 1) * E / MCH;
  const long long a0 = min((cb + 3) & ~3LL, ce);
  const long long nv = (ce - a0) >> 2;
  for (long long e = cb + threadIdx.x; e < a0; e += blockDim.x) {
    int d = edst[e] - base;
    if ((unsigned)d < (unsigned)lim) csr[atomicAdd(&cur[d], 1)] = esrc[e];
  }
  const int4* __restrict__ d4p = (const int4*)(edst + a0);
  const int4* __restrict__ s4p = (const int4*)(esrc + a0);
  for (long long i = threadIdx.x; i < nv; i += blockDim.x) {
    int4 d4 = d4p[i];
    int4 s4 = s4p[i];
    int d;
    d = d4.x - base; if ((unsigned)d < (unsigned)lim) csr[atomicAdd(&cur[d], 1)] = s4.x;
    d = d4.y - base; if ((unsigned)d < (unsigned)lim) csr[atomicAdd(&cur[d], 1)] = s4.y;
    d = d4.z - base; if ((unsigned)d < (unsigned)lim) csr[atomicAdd(&cur[d], 1)] = s4.z;
    d = d4.w - base; if ((unsigned)d < (unsigned)lim) csr[atomicAdd(&cur[d], 1)] = s4.w;
  }
  for (long long e = a0 + (nv << 2) + threadIdx.x; e < ce; e += blockDim.x) {
    int d = edst[e] - base;
    if ((unsigned)d < (unsigned)lim) csr[atomicAdd(&cur[d], 1)] = esrc[e];
  }
}

// ------------------------------------------------- (N,64) @ (64,64) GEMM
// 256-thread blocks = 4 independent waves (R9: 64-thread blocks capped
// occupancy at ~6 waves/CU).  Per wave: W column in 64 VGPRs, 4 rows via
// wave-uniform scalar loads, 4 independent FMA streams.
__global__ void __launch_bounds__(256) k_gemm64(
    const float* __restrict__ in, const float* __restrict__ norm,
    const float* __restrict__ W, float* __restrict__ out, int N) {
  const int lane = threadIdx.x & 63;
  const int gw = blockIdx.x * 4 + (threadIdx.x >> 6);
  const int nw = gridDim.x * 4;
  float w[64];
#pragma unroll
  for (int k = 0; k < 64; ++k) w[k] = W[k * 64 + lane];   // coalesced
  const int ngrp = (N + 3) >> 2;
  for (int g = gw; g < ngrp; g += nw) {
    const int v0 = g << 2;
    if (v0 + 4 <= N) {
      const float* __restrict__ r0 = in + (size_t)v0 * 64;
      const float* __restrict__ r1 = r0 + 64;
      const float* __restrict__ r2 = r0 + 128;
      const float* __restrict__ r3 = r0 + 192;
      float a0 = 0.f, a1 = 0.f, a2 = 0.f, a3 = 0.f;
#pragma unroll
      for (int k = 0; k < 64; ++k) {
        a0 = fmaf(r0[k], w[k], a0);
        a1 = fmaf(r1[k], w[k], a1);
        a2 = fmaf(r2[k], w[k], a2);
        a3 = fmaf(r3[k], w[k], a3);
      }
      out[(size_t)v0 * 64 + lane]       = a0 * norm[v0];
      out[(size_t)v0 * 64 + 64 + lane]  = a1 * norm[v0 + 1];
      out[(size_t)v0 * 64 + 128 + lane] = a2 * norm[v0 + 2];
      out[(size_t)v0 * 64 + 192 + lane] = a3 * norm[v0 + 3];
    } else {
      for (int v = v0; v < N; ++v) {
        const float* __restrict__ row = in + (size_t)v * 64;
        float acc = 0.f;
#pragma unroll
        for (int k = 0; k < 64; ++k) acc = fmaf(row[k], w[k], acc);
        out[(size_t)v * 64 + lane] = acc * norm[v];
      }
    }
  }
}

// ---------------------------------------- CSR gather + fused epilogue
__global__ void k_gather(const float* __restrict__ m, const int* __restrict__ rowptr,
                         const int* __restrict__ deg, const float* __restrict__ norm_d,
                         const float* __restrict__ bias, const int* __restrict__ csr,
                         float* __restrict__ h, float* __restrict__ key, int N) {
  const int w = blockIdx.x * (blockDim.x >> 6) + (threadIdx.x >> 6);
  if (w >= N) return;
  const int lane = threadIdx.x & 63;
  const int quad = lane & 15;
  const int grp = lane >> 4;
  const int start = rowptr[w];
  const int cnt = deg[w];
  float4 acc0 = make_float4(0.f, 0.f, 0.f, 0.f);
  float4 acc1 = make_float4(0.f, 0.f, 0.f, 0.f);
  int i = grp;
  for (; i + 4 < cnt; i += 8) {
    int s0 = csr[start + i];
    int s1 = csr[start + i + 4];
    const float4 v0 = *(const float4*)(m + (size_t)s0 * 64 + quad * 4);
    const float4 v1 = *(const float4*)(m + (size_t)s1 * 64 + quad * 4);
    acc0.x += v0.x; acc0.y += v0.y; acc0.z += v0.z; acc0.w += v0.w;
    acc1.x += v1.x; acc1.y += v1.y; acc1.z += v1.z; acc1.w += v1.w;
  }
  if (i < cnt) {
    int s0 = csr[start + i];
    const float4 v0 = *(const float4*)(m + (size_t)s0 * 64 + quad * 4);
    acc0.x += v0.x; acc0.y += v0.y; acc0.z += v0.z; acc0.w += v0.w;
  }
  acc0.x += acc1.x; acc0.y += acc1.y; acc0.z += acc1.z; acc0.w += acc1.w;
#pragma unroll
  for (int off = 16; off <= 32; off <<= 1) {
    acc0.x += __shfl_xor(acc0.x, off, 64);
    acc0.y += __shfl_xor(acc0.y, off, 64);
    acc0.z += __shfl_xor(acc0.z, off, 64);
    acc0.w += __shfl_xor(acc0.w, off, 64);
  }
  const float nd = norm_d[w];
  const float4 bq = *(const float4*)(bias + quad * 4);
  float4 o;
  o.x = fmaxf(fmaf(acc0.x, nd, bq.x), 0.f);
  o.y = fmaxf(fmaf(acc0.y, nd, bq.y), 0.f);
  o.z = fmaxf(fmaf(acc0.z, nd, bq.z), 0.f);
  o.w = fmaxf(fmaf(acc0.w, nd, bq.w), 0.f);
  if (grp == 0) *(float4*)(h + (size_t)w * 64 + quad * 4) = o;
  if (key != nullptr) {
    float mx = fmaxf(fmaxf(o.x, o.y), fmaxf(o.z, o.w));
#pragma unroll
    for (int off = 1; off < 16; off <<= 1) mx = fmaxf(mx, __shfl_xor(mx, off, 64));
    if (lane == 0) key[w] = mx;
  }
}

// ------------------------------------------- per-graph ranges (no atomics)
__global__ void k_bstart(const int* __restrict__ gid, int* __restrict__ gstart, int N) {
  int i = blockIdx.x * blockDim.x + threadIdx.x;
  if (i >= N) return;
  int g = gid[i];
  if (i == 0 || gid[i - 1] != g) gstart[g] = i;
}

__global__ void k_bfin(const int* __restrict__ gstart, int* __restrict__ gcnt,
                       int B, int N) {
  __shared__ int sm[512];
  const int g = threadIdx.x;
  sm[g] = (g < B) ? gstart[g] : 0x7fffffff;
  __syncthreads();
  for (int off = 1; off < 512; off <<= 1) {
    int x = (g + off < 512) ? sm[g + off] : 0x7fffffff;
    __syncthreads();
    sm[g] = min(sm[g], x);
    __syncthreads();
  }
  if (g < B) {
    int gs = gstart[g];
    int ns = (g + 1 < 512) ? min(sm[g + 1], N) : N;
    gcnt[g] = (gs < N) ? (ns - gs) : 0;
  }
}

// --------------------------------------------------- top-3 keys per graph
__global__ void k_top3(const float* __restrict__ key, const int* __restrict__ gstart,
                       const int* __restrict__ gcnt, int* __restrict__ sel, int B) {
  const int lane = threadIdx.x & 63;
  const int g = blockIdx.x * (blockDim.x >> 6) + (threadIdx.x >> 6);
  if (g >= B) return;
  const int s = gstart[g], c = gcnt[g];
  float v0 = -1.f, v1 = -1.f, v2 = -1.f;
  int i0 = 0x7fffffff, i1 = 0x7fffffff, i2 = 0x7fffffff;
  for (int i = s + lane; i < s + c; i += 64) {
    float kv = key[i];
    if (kv > v0 || (kv == v0 && i < i0)) {
      v2 = v1; i2 = i1; v1 = v0; i1 = i0; v0 = kv; i0 = i;
    } else if (kv > v1 || (kv == v1 && i < i1)) {
      v2 = v1; i2 = i1; v1 = kv; i1 = i;
    } else if (kv > v2 || (kv == v2 && i < i2)) {
      v2 = kv; i2 = i;
    }
  }
  int ptr = 0;
  for (int r = 0; r < 3; ++r) {
    float mv = (ptr == 0) ? v0 : (ptr == 1) ? v1 : (ptr == 2) ? v2 : -1.f;
    int   mi = (ptr == 0) ? i0 : (ptr == 1) ? i1 : (ptr == 2) ? i2 : 0x7fffffff;
    float bv = mv; int bi = mi;
#pragma unroll
    for (int off = 32; off; off >>= 1) {
      float ov = __shfl_xor(bv, off, 64);
      int   oi = __shfl_xor(bi, off, 64);
      if (ov > bv || (ov == bv && oi < bi)) { bv = ov; bi = oi; }
    }
    if (bi == mi && ptr < 3) ptr++;             // winner's owner pops
    if (lane == 0) sel[g * 3 + r] = (bi == 0x7fffffff) ? -1 : bi;
  }
}

// ------------------------------------- gather selected rows + bitonic sort
__global__ void k_pool(const float* __restrict__ h, const int* __restrict__ sel,
                       float* __restrict__ p, int B) {
  const int lane = threadIdx.x & 63;
  const int w = blockIdx.x * (blockDim.x >> 6) + (threadIdx.x >> 6);
  if (w >= B * 3) return;
  int node = sel[w];
  float v = 0.f;
  if (node >= 0) {
    v = h[(size_t)node * 64 + lane];
    for (int k2 = 2; k2 <= 64; k2 <<= 1) {
      for (int j = k2 >> 1; j > 0; j >>= 1) {
        float o = __shfl_xor(v, j, 64);
        bool up = ((lane & k2) == 0);
        bool lower = ((lane & j) == 0);
        v = (lower == up) ? fminf(v, o) : fmaxf(v, o);
      }
    }
  }
  p[(size_t)w * 64 + lane] = v;
}

// ---------------------------------------------------------- classifier
__global__ void k_cls(const float* __restrict__ p, const float* __restrict__ cw,
                      const float* __restrict__ cb, const float* __restrict__ Wc,
                      const float* __restrict__ bc, float* __restrict__ out, int B) {
  __shared__ float prow[192];
  const int b = blockIdx.x;
  const int lane = threadIdx.x;
  prow[lane] = p[(size_t)b * 192 + lane];
  prow[lane + 64] = p[(size_t)b * 192 + lane + 64];
  prow[lane + 128] = p[(size_t)b * 192 + lane + 128];
  __syncthreads();
  float y = cb[lane];
  for (int j = 0; j < 192; ++j) y = fmaf(prow[j], cw[lane * 192 + j], y);
  float ry = fmaxf(y, 0.f);
  for (int c = 0; c < 10; ++c) {
    float s = ry * Wc[lane * 10 + c];
#pragma unroll
    for (int off = 32; off; off >>= 1) s += __shfl_xor(s, off, 64);
    if (lane == 0) out[b * 10 + c] = s + bc[c];
  }
}

// ================================================================ launch
extern "C" void kernel_launch(void* const* d_in, const int* in_sizes, int n_in,
                              void* d_out, int out_size, void* d_ws, size_t ws_size,
                              hipStream_t stream) {
  const float* features = (const float*)d_in[0];
  const int*   esrc     = (const int*)d_in[1];
  const int*   edst     = (const int*)d_in[2];
  const int*   gid      = (const int*)d_in[3];
  const float* W1 = (const float*)d_in[5];
  const float* b1 = (const float*)d_in[6];
  const float* W2 = (const float*)d_in[7];
  const float* b2 = (const float*)d_in[8];
  const float* cw = (const float*)d_in[9];
  const float* cb = (const float*)d_in[10];
  const float* Wc = (const float*)d_in[11];
  const float* bc = (const float*)d_in[12];
  float* out = (float*)d_out;

  const int N = in_sizes[0] / 64;
  const int E = in_sizes[1];
  const int B = out_size / 10;
  const size_t N64 = (size_t)N * 64;
  const int nscan = (N + 2047) / 2048;       // <= 64 for N <= 131072
  const int P = (N + PART - 1) / PART;       // 16 for N=100k
  const size_t HSZ = (size_t)P * MCH * PART; // u8 hist bytes (~6.4 MB)

  // workspace carve-up (~75 MB of the 256 MB ws; fully disjoint).
  float* bufA   = (float*)d_ws;            // N*64 : m1 -> m2
  float* bufB   = bufA + N64;              // N*64 : h1 -> h2
  int*   deg_d  = (int*)(bufB + N64);      // N
  float* norm_s = (float*)(deg_d + N);     // N
  float* norm_d = norm_s + N;              // N
  float* key    = norm_d + N;              // N
  int*   rowptr = (int*)(key + N);         // N
  int*   csr    = rowptr + N;              // E
  int*   bsum   = csr + E;                 // <=64
  int*   gstart = bsum + 64;               // B
  int*   gcnt   = gstart + B;              // B
  int*   sel    = gcnt + B;                // 3B
  float* p      = (float*)(sel + 3 * B);   // 192B
  unsigned char* hd = (unsigned char*)(p + 192 * B); // HSZ u8
  unsigned char* hs = hd + HSZ;                      // HSZ u8

  const int TB = 256;

  // ---- CSR build (no global atomics)
  k_hist2<<<P * MCH, TB, 0, stream>>>(esrc, edst, hd, hs, N, E, P);
  k_off<<<(N + TB - 1) / TB, TB, 0, stream>>>(hd, hs, deg_d, norm_s, norm_d, N, P);
  k_scan1<<<nscan, 256, 0, stream>>>(deg_d, rowptr, bsum, N);
  k_scan2<<<1, 64, 0, stream>>>(bsum, nscan);
  k_scan3<<<(N + TB - 1) / TB, TB, 0, stream>>>(rowptr, bsum, N);
  k_fill2<<<P * MCH, TB, 0, stream>>>(esrc, edst, hd, rowptr, csr, N, E, P);

  // ---- layer 1
  k_gemm64<<<1536, TB, 0, stream>>>(features, norm_s, W1, bufA, N);
  k_gather<<<(N + 3) / 4, TB, 0, stream>>>(bufA, rowptr, deg_d, norm_d, b1, csr,
                                           bufB, nullptr, N);

  // ---- layer 2 (key = row max fused)
  k_gemm64<<<1536, TB, 0, stream>>>(bufB, norm_s, W2, bufA, N);
  k_gather<<<(N + 3) / 4, TB, 0, stream>>>(bufA, rowptr, deg_d, norm_d, b2, csr,
                                           bufB, key, N);

  // ---- sort-pool (boundary detection on sorted gid; no atomics)
  hipMemsetAsync(gstart, 0x7f, (size_t)B * sizeof(int), stream);
  k_bstart<<<(N + TB - 1) / TB, TB, 0, stream>>>(gid, gstart, N);
  k_bfin<<<1, 512, 0, stream>>>(gstart, gcnt, B, N);
  k_top3<<<(B + 3) / 4, TB, 0, stream>>>(key, gstart, gcnt, sel, B);
  k_pool<<<(B * 3 + 3) / 4, TB, 0, stream>>>(bufB, sel, p, B);

  // ---- classifier
  k_cls<<<B, 64, 0, stream>>>(p, cw, cb, Wc, bc, out, B);
}

// Round 11
// 322.874 us; speedup vs baseline: 1.2281x; 1.2281x over previous
//
#include <hip/hip_runtime.h>
#include <hip/hip_bf16.h>

// Problem constants (reference): IN_DIM = HID = 64, K = 3, NCLS = 10.
// All compute fp32. Output fp32 (B*10).
//
// CSR build (no global atomics; counting sort by dst):
//   P=16 node partitions (PART=6272), XCD-pinned (p = blockIdx % P keeps
//   partition p on XCD p%8 -> csr writes merge in one L2).  MCH=64 edge
//   chunks; u8 chunk-offset metadata; u16-packed LDS counters + int4 loads.
//
// GEMM (R10 post-mortem: scalar-load trick broke under 256-thread blocks,
// and even the working R9 version serialized on SGPR-chunked s_loads):
// LDS-tiled — 128-node tile/block, W in LDS (16KB), A staged COLUMN-MAJOR
// (stride 136 -> conflict-free b128 reads in the hot loop), each thread
// 4 nodes x 8 channels in registers.  50KB LDS -> 3 blocks/CU.

#define PART 6272
#define HALFP (PART / 2)
#define MCH  64

// --------------------------- merged src+dst histogram (one edge pass)
__global__ void k_hist2(const int* __restrict__ esrc, const int* __restrict__ edst,
                        unsigned char* __restrict__ hd, unsigned char* __restrict__ hs,
                        int N, int E, int P) {
  __shared__ unsigned int ld[HALFP];
  __shared__ unsigned int ls[HALFP];
  const int b = blockIdx.x;
  const int p = b % P;
  const int m = b / P;
  const int base = p * PART;
  const int lim = min(PART, N - base);
  for (int i = threadIdx.x; i < HALFP; i += blockDim.x) { ld[i] = 0u; ls[i] = 0u; }
  __syncthreads();
  const long long cb = (long long)m * E / MCH;
  const long long ce = (long long)(m + 1) * E / MCH;
  const long long a0 = min((cb + 3) & ~3LL, ce);
  const long long nv = (ce - a0) >> 2;
  for (long long e = cb + threadIdx.x; e < a0; e += blockDim.x) {
    int d = edst[e] - base;
    if ((unsigned)d < (unsigned)lim) atomicAdd(&ld[d >> 1], 1u << ((d & 1) * 16));
    int s = esrc[e] - base;
    if ((unsigned)s < (unsigned)lim) atomicAdd(&ls[s >> 1], 1u << ((s & 1) * 16));
  }
  const int4* __restrict__ d4p = (const int4*)(edst + a0);
  const int4* __restrict__ s4p = (const int4*)(esrc + a0);
  for (long long i = threadIdx.x; i < nv; i += blockDim.x) {
    int4 d4 = d4p[i];
    int4 s4 = s4p[i];
    int d;
    d = d4.x - base; if ((unsigned)d < (unsigned)lim) atomicAdd(&ld[d >> 1], 1u << ((d & 1) * 16));
    d = d4.y - base; if ((unsigned)d < (unsigned)lim) atomicAdd(&ld[d >> 1], 1u << ((d & 1) * 16));
    d = d4.z - base; if ((unsigned)d < (unsigned)lim) atomicAdd(&ld[d >> 1], 1u << ((d & 1) * 16));
    d = d4.w - base; if ((unsigned)d < (unsigned)lim) atomicAdd(&ld[d >> 1], 1u << ((d & 1) * 16));
    d = s4.x - base; if ((unsigned)d < (unsigned)lim) atomicAdd(&ls[d >> 1], 1u << ((d & 1) * 16));
    d = s4.y - base; if ((unsigned)d < (unsigned)lim) atomicAdd(&ls[d >> 1], 1u << ((d & 1) * 16));
    d = s4.z - base; if ((unsigned)d < (unsigned)lim) atomicAdd(&ls[d >> 1], 1u << ((d & 1) * 16));
    d = s4.w - base; if ((unsigned)d < (unsigned)lim) atomicAdd(&ls[d >> 1], 1u << ((d & 1) * 16));
  }
  for (long long e = a0 + (nv << 2) + threadIdx.x; e < ce; e += blockDim.x) {
    int d = edst[e] - base;
    if ((unsigned)d < (unsigned)lim) atomicAdd(&ld[d >> 1], 1u << ((d & 1) * 16));
    int s = esrc[e] - base;
    if ((unsigned)s < (unsigned)lim) atomicAdd(&ls[s >> 1], 1u << ((s & 1) * 16));
  }
  __syncthreads();
  unsigned char* sd = hd + ((size_t)p * MCH + m) * PART;
  unsigned char* ss = hs + ((size_t)p * MCH + m) * PART;
  for (int i = threadIdx.x; i < lim; i += blockDim.x) {
    sd[i] = (unsigned char)((ld[i >> 1] >> ((i & 1) * 16)) & 0xffffu);
    ss[i] = (unsigned char)((ls[i >> 1] >> ((i & 1) * 16)) & 0xffffu);
  }
}

// ---------------- counts -> in-row prefix offsets (u8, in place) + degs/norms
__global__ void k_off(unsigned char* __restrict__ hd, const unsigned char* __restrict__ hs,
                      int* __restrict__ deg_d, float* __restrict__ norm_s,
                      float* __restrict__ norm_d, int N, int P) {
  int v = blockIdx.x * blockDim.x + threadIdx.x;
  if (v >= N) return;
  int p = v / PART, loc = v % PART;
  size_t base = (size_t)p * MCH * PART + loc;
  int run = 0;
#pragma unroll
  for (int m = 0; m < MCH; ++m) {
    int t = hd[base + (size_t)m * PART];
    hd[base + (size_t)m * PART] = (unsigned char)run;
    run += t;
  }
  int s = 0;
#pragma unroll
  for (int m = 0; m < MCH; ++m) s += hs[base + (size_t)m * PART];
  deg_d[v] = run;
  norm_d[v] = rsqrtf((float)max(run, 1));
  norm_s[v] = rsqrtf((float)max(s, 1));
}

// ------------------------------------------------------------ CSR scan
__global__ void k_scan1(const int* __restrict__ deg, int* __restrict__ rowptr,
                        int* __restrict__ bsum, int N) {
  __shared__ int sums[256];
  const int t = threadIdx.x;
  const int base = blockIdx.x * 2048 + t * 8;
  int loc[8];
  int tot = 0;
#pragma unroll
  for (int j = 0; j < 8; ++j) {
    int idx = base + j;
    loc[j] = tot;
    tot += (idx < N) ? deg[idx] : 0;
  }
  sums[t] = tot;
  __syncthreads();
  for (int off = 1; off < 256; off <<= 1) {
    int x = (t >= off) ? sums[t - off] : 0;
    __syncthreads();
    sums[t] += x;
    __syncthreads();
  }
  int excl = (t == 0) ? 0 : sums[t - 1];
#pragma unroll
  for (int j = 0; j < 8; ++j) {
    int idx = base + j;
    if (idx < N) rowptr[idx] = excl + loc[j];
  }
  if (t == 255) bsum[blockIdx.x] = sums[255];
}

__global__ void k_scan2(int* __restrict__ bsum, int nb) {
  int lane = threadIdx.x;
  int v = (lane < nb) ? bsum[lane] : 0;
  int inc = v;
#pragma unroll
  for (int off = 1; off < 64; off <<= 1) {
    int o = __shfl_up(inc, off, 64);
    if (lane >= off) inc += o;
  }
  if (lane < nb) bsum[lane] = inc - v;
}

__global__ void k_scan3(int* __restrict__ rowptr, const int* __restrict__ bsum, int N) {
  int v = blockIdx.x * blockDim.x + threadIdx.x;
  if (v < N) rowptr[v] += bsum[v >> 11];
}

// ----------------------------------------- fill (LDS cursors, no atomics)
__global__ void k_fill2(const int* __restrict__ esrc, const int* __restrict__ edst,
                        const unsigned char* __restrict__ hd, const int* __restrict__ rowptr,
                        int* __restrict__ csr, int N, int E, int P) {
  __shared__ int cur[PART];
  const int b = blockIdx.x;
  const int p = b % P;
  const int m = b / P;
  const int base = p * PART;
  const int lim = min(PART, N - base);
  const unsigned char* slice = hd + ((size_t)p * MCH + m) * PART;
  for (int i = threadIdx.x; i < lim; i += blockDim.x)
    cur[i] = rowptr[base + i] + (int)slice[i];
  __syncthreads();
  const long long cb = (long long)m * E / MCH;
  const long long ce = (long long)(m + 1) * E / MCH;
  const long long a0 = min((cb + 3) & ~3LL, ce);
  const long long nv = (ce - a0) >> 2;
  for (long long e = cb + threadIdx.x; e < a0; e += blockDim.x) {
    int d = edst[e] - base;
    if ((unsigned)d < (unsigned)lim) csr[atomicAdd(&cur[d], 1)] = esrc[e];
  }
  const int4* __restrict__ d4p = (const int4*)(edst + a0);
  const int4* __restrict__ s4p = (const int4*)(esrc + a0);
  for (long long i = threadIdx.x; i < nv; i += blockDim.x) {
    int4 d4 = d4p[i];
    int4 s4 = s4p[i];
    int d;
    d = d4.x - base; if ((unsigned)d < (unsigned)lim) csr[atomicAdd(&cur[d], 1)] = s4.x;
    d = d4.y - base; if ((unsigned)d < (unsigned)lim) csr[atomicAdd(&cur[d], 1)] = s4.y;
    d = d4.z - base; if ((unsigned)d < (unsigned)lim) csr[atomicAdd(&cur[d], 1)] = s4.z;
    d = d4.w - base; if ((unsigned)d < (unsigned)lim) csr[atomicAdd(&cur[d], 1)] = s4.w;
  }
  for (long long e = a0 + (nv << 2) + threadIdx.x; e < ce; e += blockDim.x) {
    int d = edst[e] - base;
    if ((unsigned)d < (unsigned)lim) csr[atomicAdd(&cur[d], 1)] = esrc[e];
  }
}

// ------------------------------------------------- (N,64) @ (64,64) GEMM
// LDS-tiled: 128-node tile per 256-thread block.  A staged column-major
// Ac[k][node] (stride 136 -> hot-loop ds_read_b128 conflict-free; bank map
// verified: 8 node-groups x 4 dwords cover all 32 banks once).  Each thread
// owns 4 nodes x 8 channels.  out[v][o] = (sum_k in[v][k]*W[k][o]) * norm[v].
__global__ void __launch_bounds__(256) k_gemm64(
    const float* __restrict__ in, const float* __restrict__ norm,
    const float* __restrict__ W, float* __restrict__ out, int N) {
  __shared__ float Wl[4096];        // W[k][o], 16 KB
  __shared__ float Ac[64 * 136];    // Ac[k*136 + node], 34.8 KB
  const int t = threadIdx.x;
  const int ch = (t & 7) * 8;       // channel base (0..56)
  const int nb = (t >> 3) * 4;      // node base within tile (0..124)
  for (int i = t; i < 1024; i += 256)
    ((float4*)Wl)[i] = ((const float4*)W)[i];

  const int NT = (N + 127) >> 7;
  for (int tile = blockIdx.x; tile < NT; tile += gridDim.x) {
    const int vbase = tile << 7;
    __syncthreads();                 // Ac reuse + W ready on first pass
    // stage A column-major: thread reads float4 of row r, scatters to 4 k-rows
    for (int i = t; i < 2048; i += 256) {
      const int r = i >> 4;
      const int c = (i & 15) * 4;
      const int v = vbase + r;
      float4 val = make_float4(0.f, 0.f, 0.f, 0.f);
      if (v < N) val = *(const float4*)(in + (size_t)v * 64 + c);
      Ac[(c + 0) * 136 + r] = val.x;
      Ac[(c + 1) * 136 + r] = val.y;
      Ac[(c + 2) * 136 + r] = val.z;
      Ac[(c + 3) * 136 + r] = val.w;
    }
    __syncthreads();

    float acc[4][8];
#pragma unroll
    for (int j = 0; j < 4; ++j)
#pragma unroll
      for (int c = 0; c < 8; ++c) acc[j][c] = 0.f;

    for (int k = 0; k < 64; k += 4) {
#pragma unroll
      for (int kk = 0; kk < 4; ++kk) {
        const float4 aa = *(const float4*)&Ac[(k + kk) * 136 + nb];
        const float4 w0 = *(const float4*)&Wl[(k + kk) * 64 + ch];
        const float4 w1 = *(const float4*)&Wl[(k + kk) * 64 + ch + 4];
        const float an[4] = {aa.x, aa.y, aa.z, aa.w};
        const float wn[8] = {w0.x, w0.y, w0.z, w0.w, w1.x, w1.y, w1.z, w1.w};
#pragma unroll
        for (int j = 0; j < 4; ++j)
#pragma unroll
          for (int c = 0; c < 8; ++c)
            acc[j][c] = fmaf(an[j], wn[c], acc[j][c]);
      }
    }

#pragma unroll
    for (int j = 0; j < 4; ++j) {
      const int v = vbase + nb + j;
      if (v < N) {
        const float nm = norm[v];
        float4 o0, o1;
        o0.x = acc[j][0] * nm; o0.y = acc[j][1] * nm;
        o0.z = acc[j][2] * nm; o0.w = acc[j][3] * nm;
        o1.x = acc[j][4] * nm; o1.y = acc[j][5] * nm;
        o1.z = acc[j][6] * nm; o1.w = acc[j][7] * nm;
        *(float4*)(out + (size_t)v * 64 + ch)     = o0;
        *(float4*)(out + (size_t)v * 64 + ch + 4) = o1;
      }
    }
  }
}

// ---------------------------------------- CSR gather + fused epilogue
__global__ void k_gather(const float* __restrict__ m, const int* __restrict__ rowptr,
                         const int* __restrict__ deg, const float* __restrict__ norm_d,
                         const float* __restrict__ bias, const int* __restrict__ csr,
                         float* __restrict__ h, float* __restrict__ key, int N) {
  const int w = blockIdx.x * (blockDim.x >> 6) + (threadIdx.x >> 6);
  if (w >= N) return;
  const int lane = threadIdx.x & 63;
  const int quad = lane & 15;
  const int grp = lane >> 4;
  const int start = rowptr[w];
  const int cnt = deg[w];
  float4 acc0 = make_float4(0.f, 0.f, 0.f, 0.f);
  float4 acc1 = make_float4(0.f, 0.f, 0.f, 0.f);
  int i = grp;
  for (; i + 4 < cnt; i += 8) {
    int s0 = csr[start + i];
    int s1 = csr[start + i + 4];
    const float4 v0 = *(const float4*)(m + (size_t)s0 * 64 + quad * 4);
    const float4 v1 = *(const float4*)(m + (size_t)s1 * 64 + quad * 4);
    acc0.x += v0.x; acc0.y += v0.y; acc0.z += v0.z; acc0.w += v0.w;
    acc1.x += v1.x; acc1.y += v1.y; acc1.z += v1.z; acc1.w += v1.w;
  }
  if (i < cnt) {
    int s0 = csr[start + i];
    const float4 v0 = *(const float4*)(m + (size_t)s0 * 64 + quad * 4);
    acc0.x += v0.x; acc0.y += v0.y; acc0.z += v0.z; acc0.w += v0.w;
  }
  acc0.x += acc1.x; acc0.y += acc1.y; acc0.z += acc1.z; acc0.w += acc1.w;
#pragma unroll
  for (int off = 16; off <= 32; off <<= 1) {
    acc0.x += __shfl_xor(acc0.x, off, 64);
    acc0.y += __shfl_xor(acc0.y, off, 64);
    acc0.z += __shfl_xor(acc0.z, off, 64);
    acc0.w += __shfl_xor(acc0.w, off, 64);
  }
  const float nd = norm_d[w];
  const float4 bq = *(const float4*)(bias + quad * 4);
  float4 o;
  o.x = fmaxf(fmaf(acc0.x, nd, bq.x), 0.f);
  o.y = fmaxf(fmaf(acc0.y, nd, bq.y), 0.f);
  o.z = fmaxf(fmaf(acc0.z, nd, bq.z), 0.f);
  o.w = fmaxf(fmaf(acc0.w, nd, bq.w), 0.f);
  if (grp == 0) *(float4*)(h + (size_t)w * 64 + quad * 4) = o;
  if (key != nullptr) {
    float mx = fmaxf(fmaxf(o.x, o.y), fmaxf(o.z, o.w));
#pragma unroll
    for (int off = 1; off < 16; off <<= 1) mx = fmaxf(mx, __shfl_xor(mx, off, 64));
    if (lane == 0) key[w] = mx;
  }
}

// ------------------------------------------- per-graph ranges (no atomics)
__global__ void k_bstart(const int* __restrict__ gid, int* __restrict__ gstart, int N) {
  int i = blockIdx.x * blockDim.x + threadIdx.x;
  if (i >= N) return;
  int g = gid[i];
  if (i == 0 || gid[i - 1] != g) gstart[g] = i;
}

__global__ void k_bfin(const int* __restrict__ gstart, int* __restrict__ gcnt,
                       int B, int N) {
  __shared__ int sm[512];
  const int g = threadIdx.x;
  sm[g] = (g < B) ? gstart[g] : 0x7fffffff;
  __syncthreads();
  for (int off = 1; off < 512; off <<= 1) {
    int x = (g + off < 512) ? sm[g + off] : 0x7fffffff;
    __syncthreads();
    sm[g] = min(sm[g], x);
    __syncthreads();
  }
  if (g < B) {
    int gs = gstart[g];
    int ns = (g + 1 < 512) ? min(sm[g + 1], N) : N;
    gcnt[g] = (gs < N) ? (ns - gs) : 0;
  }
}

// --------------------------------------------------- top-3 keys per graph
__global__ void k_top3(const float* __restrict__ key, const int* __restrict__ gstart,
                       const int* __restrict__ gcnt, int* __restrict__ sel, int B) {
  const int lane = threadIdx.x & 63;
  const int g = blockIdx.x * (blockDim.x >> 6) + (threadIdx.x >> 6);
  if (g >= B) return;
  const int s = gstart[g], c = gcnt[g];
  float v0 = -1.f, v1 = -1.f, v2 = -1.f;
  int i0 = 0x7fffffff, i1 = 0x7fffffff, i2 = 0x7fffffff;
  for (int i = s + lane; i < s + c; i += 64) {
    float kv = key[i];
    if (kv > v0 || (kv == v0 && i < i0)) {
      v2 = v1; i2 = i1; v1 = v0; i1 = i0; v0 = kv; i0 = i;
    } else if (kv > v1 || (kv == v1 && i < i1)) {
      v2 = v1; i2 = i1; v1 = kv; i1 = i;
    } else if (kv > v2 || (kv == v2 && i < i2)) {
      v2 = kv; i2 = i;
    }
  }
  int ptr = 0;
  for (int r = 0; r < 3; ++r) {
    float mv = (ptr == 0) ? v0 : (ptr == 1) ? v1 : (ptr == 2) ? v2 : -1.f;
    int   mi = (ptr == 0) ? i0 : (ptr == 1) ? i1 : (ptr == 2) ? i2 : 0x7fffffff;
    float bv = mv; int bi = mi;
#pragma unroll
    for (int off = 32; off; off >>= 1) {
      float ov = __shfl_xor(bv, off, 64);
      int   oi = __shfl_xor(bi, off, 64);
      if (ov > bv || (ov == bv && oi < bi)) { bv = ov; bi = oi; }
    }
    if (bi == mi && ptr < 3) ptr++;             // winner's owner pops
    if (lane == 0) sel[g * 3 + r] = (bi == 0x7fffffff) ? -1 : bi;
  }
}

// ------------------------------------- gather selected rows + bitonic sort
__global__ void k_pool(const float* __restrict__ h, const int* __restrict__ sel,
                       float* __restrict__ p, int B) {
  const int lane = threadIdx.x & 63;
  const int w = blockIdx.x * (blockDim.x >> 6) + (threadIdx.x >> 6);
  if (w >= B * 3) return;
  int node = sel[w];
  float v = 0.f;
  if (node >= 0) {
    v = h[(size_t)node * 64 + lane];
    for (int k2 = 2; k2 <= 64; k2 <<= 1) {
      for (int j = k2 >> 1; j > 0; j >>= 1) {
        float o = __shfl_xor(v, j, 64);
        bool up = ((lane & k2) == 0);
        bool lower = ((lane & j) == 0);
        v = (lower == up) ? fminf(v, o) : fmaxf(v, o);
      }
    }
  }
  p[(size_t)w * 64 + lane] = v;
}

// ---------------------------------------------------------- classifier
__global__ void k_cls(const float* __restrict__ p, const float* __restrict__ cw,
                      const float* __restrict__ cb, const float* __restrict__ Wc,
                      const float* __restrict__ bc, float* __restrict__ out, int B) {
  __shared__ float prow[192];
  const int b = blockIdx.x;
  const int lane = threadIdx.x;
  prow[lane] = p[(size_t)b * 192 + lane];
  prow[lane + 64] = p[(size_t)b * 192 + lane + 64];
  prow[lane + 128] = p[(size_t)b * 192 + lane + 128];
  __syncthreads();
  float y = cb[lane];
  for (int j = 0; j < 192; ++j) y = fmaf(prow[j], cw[lane * 192 + j], y);
  float ry = fmaxf(y, 0.f);
  for (int c = 0; c < 10; ++c) {
    float s = ry * Wc[lane * 10 + c];
#pragma unroll
    for (int off = 32; off; off >>= 1) s += __shfl_xor(s, off, 64);
    if (lane == 0) out[b * 10 + c] = s + bc[c];
  }
}

// ================================================================ launch
extern "C" void kernel_launch(void* const* d_in, const int* in_sizes, int n_in,
                              void* d_out, int out_size, void* d_ws, size_t ws_size,
                              hipStream_t stream) {
  const float* features = (const float*)d_in[0];
  const int*   esrc     = (const int*)d_in[1];
  const int*   edst     = (const int*)d_in[2];
  const int*   gid      = (const int*)d_in[3];
  const float* W1 = (const float*)d_in[5];
  const float* b1 = (const float*)d_in[6];
  const float* W2 = (const float*)d_in[7];
  const float* b2 = (const float*)d_in[8];
  const float* cw = (const float*)d_in[9];
  const float* cb = (const float*)d_in[10];
  const float* Wc = (const float*)d_in[11];
  const float* bc = (const float*)d_in[12];
  float* out = (float*)d_out;

  const int N = in_sizes[0] / 64;
  const int E = in_sizes[1];
  const int B = out_size / 10;
  const size_t N64 = (size_t)N * 64;
  const int nscan = (N + 2047) / 2048;       // <= 64 for N <= 131072
  const int P = (N + PART - 1) / PART;       // 16 for N=100k
  const size_t HSZ = (size_t)P * MCH * PART; // u8 hist bytes (~6.4 MB)
  const int NT = (N + 127) / 128;            // gemm tiles

  // workspace carve-up (~75 MB of the 256 MB ws; fully disjoint).
  float* bufA   = (float*)d_ws;            // N*64 : m1 -> m2
  float* bufB   = bufA + N64;              // N*64 : h1 -> h2
  int*   deg_d  = (int*)(bufB + N64);      // N
  float* norm_s = (float*)(deg_d + N);     // N
  float* norm_d = norm_s + N;              // N
  float* key    = norm_d + N;              // N
  int*   rowptr = (int*)(key + N);         // N
  int*   csr    = rowptr + N;              // E
  int*   bsum   = csr + E;                 // <=64
  int*   gstart = bsum + 64;               // B
  int*   gcnt   = gstart + B;              // B
  int*   sel    = gcnt + B;                // 3B
  float* p      = (float*)(sel + 3 * B);   // 192B
  unsigned char* hd = (unsigned char*)(p + 192 * B); // HSZ u8
  unsigned char* hs = hd + HSZ;                      // HSZ u8

  const int TB = 256;

  // ---- CSR build (no global atomics)
  k_hist2<<<P * MCH, TB, 0, stream>>>(esrc, edst, hd, hs, N, E, P);
  k_off<<<(N + TB - 1) / TB, TB, 0, stream>>>(hd, hs, deg_d, norm_s, norm_d, N, P);
  k_scan1<<<nscan, 256, 0, stream>>>(deg_d, rowptr, bsum, N);
  k_scan2<<<1, 64, 0, stream>>>(bsum, nscan);
  k_scan3<<<(N + TB - 1) / TB, TB, 0, stream>>>(rowptr, bsum, N);
  k_fill2<<<P * MCH, TB, 0, stream>>>(esrc, edst, hd, rowptr, csr, N, E, P);

  // ---- layer 1
  k_gemm64<<<NT, TB, 0, stream>>>(features, norm_s, W1, bufA, N);
  k_gather<<<(N + 3) / 4, TB, 0, stream>>>(bufA, rowptr, deg_d, norm_d, b1, csr,
                                           bufB, nullptr, N);

  // ---- layer 2 (key = row max fused)
  k_gemm64<<<NT, TB, 0, stream>>>(bufB, norm_s, W2, bufA, N);
  k_gather<<<(N + 3) / 4, TB, 0, stream>>>(bufA, rowptr, deg_d, norm_d, b2, csr,
                                           bufB, key, N);

  // ---- sort-pool (boundary detection on sorted gid; no atomics)
  hipMemsetAsync(gstart, 0x7f, (size_t)B * sizeof(int), stream);
  k_bstart<<<(N + TB - 1) / TB, TB, 0, stream>>>(gid, gstart, N);
  k_bfin<<<1, 512, 0, stream>>>(gstart, gcnt, B, N);
  k_top3<<<(B + 3) / 4, TB, 0, stream>>>(key, gstart, gcnt, sel, B);
  k_pool<<<(B * 3 + 3) / 4, TB, 0, stream>>>(bufB, sel, p, B);

  // ---- classifier
  k_cls<<<B, 64, 0, stream>>>(p, cw, cb, Wc, bc, out, B);
}